// Round 1
// baseline (695.282 us; speedup 1.0000x reference)
//
#include <hip/hip_runtime.h>
#include <math.h>

#define NVEC   32768
#define DIMV   64
#define KC     8192
#define NKCH   8
#define CHK    (KC / NKCH)   // 1024
#define TILE   128
#define HW     1024
#define BPLANE 65536         // DIMV*HW

// output offsets (floats)
#define OFF_Q    0
#define OFF_IDX  2097152
#define OFF_LOSS 2129920
#define OFF_PPL  2129921
#define OFF_ACT  2129922
#define OFF_NCB  2129923
#define OFF_NCS  2654211
#define OFF_NEA  2662403

// workspace offsets (floats)
#define WS_COUNTS 0          // 8192
#define WS_SUMS   8192       // 524288
#define WS_SCAL   532480     // 8: [0]=vq acc, [1]=ntotal, [2]=plog, [3]=active
#define WS_C2     532488     // 8192
#define WS_CANDS  540680     // 262144 floats
#define WS_CANDI  802824     // 262144 ints
#define WS_ZERO_BYTES (532488 * 4)

// ---------------- c2[k] = sum_d codebook[k][d]^2 ----------------
__global__ __launch_bounds__(256) void c2_kernel(const float* __restrict__ cb,
                                                 float* __restrict__ c2) {
    const int t = threadIdx.x;
    const int k = blockIdx.x * 4 + (t >> 6);
    const int d = t & 63;
    float x = cb[(size_t)k * DIMV + d];
    float s = x * x;
    for (int off = 32; off > 0; off >>= 1) s += __shfl_down(s, off, 64);
    if (d == 0) c2[k] = s;
}

// ---------------- nearest-neighbor search over one K-chunk ----------------
__global__ __launch_bounds__(256) void nn_kernel(const float* __restrict__ z,
                                                 const float* __restrict__ cb,
                                                 const float* __restrict__ c2,
                                                 float* __restrict__ candD,
                                                 int* __restrict__ candI) {
    __shared__ __align__(16) float sc[TILE * DIMV];  // 32 KB
    __shared__ float sc2[TILE];
    const int t  = threadIdx.x;
    const int vb = blockIdx.x;  // 0..63  (512 vectors each)
    const int kc = blockIdx.y;  // 0..7   (1024 codes each)
    const int n0 = vb * 512 + t;
    const int n1 = n0 + 256;

    float v0[DIMV], v1[DIMV];
    {
        const int b0 = n0 >> 10, h0 = n0 & 1023;
        const int b1 = n1 >> 10, h1 = n1 & 1023;
        const float* p0 = z + (size_t)b0 * BPLANE + h0;
        const float* p1 = z + (size_t)b1 * BPLANE + h1;
#pragma unroll
        for (int c = 0; c < DIMV; ++c) { v0[c] = p0[c * HW]; v1[c] = p1[c * HW]; }
    }
    float v02, v12;
    {
        float a0 = 0, a1 = 0, a2 = 0, a3 = 0, b0 = 0, b1 = 0, b2 = 0, b3 = 0;
#pragma unroll
        for (int c = 0; c < DIMV; c += 4) {
            a0 = fmaf(v0[c + 0], v0[c + 0], a0);
            a1 = fmaf(v0[c + 1], v0[c + 1], a1);
            a2 = fmaf(v0[c + 2], v0[c + 2], a2);
            a3 = fmaf(v0[c + 3], v0[c + 3], a3);
            b0 = fmaf(v1[c + 0], v1[c + 0], b0);
            b1 = fmaf(v1[c + 1], v1[c + 1], b1);
            b2 = fmaf(v1[c + 2], v1[c + 2], b2);
            b3 = fmaf(v1[c + 3], v1[c + 3], b3);
        }
        v02 = (a0 + a1) + (a2 + a3);
        v12 = (b0 + b1) + (b2 + b3);
    }

    float best0 = 3.4e38f, best1 = 3.4e38f;
    int bi0 = 0, bi1 = 0;
    const int kbase = kc * CHK;

    for (int tl = 0; tl < CHK / TILE; ++tl) {
        const int k0 = kbase + tl * TILE;
        __syncthreads();
        {
            const float4* src = (const float4*)(cb + (size_t)k0 * DIMV);
            float4* dst = (float4*)sc;
#pragma unroll
            for (int i = 0; i < 8; ++i) dst[t + i * 256] = src[t + i * 256];
            if (t < TILE) sc2[t] = c2[k0 + t];
        }
        __syncthreads();

        for (int j = 0; j < TILE; ++j) {
            const float4* cj = (const float4*)(sc + j * DIMV);
            float s00 = 0, s01 = 0, s02 = 0, s03 = 0;
            float s10 = 0, s11 = 0, s12 = 0, s13 = 0;
#pragma unroll
            for (int q = 0; q < DIMV / 4; ++q) {
                float4 c4 = cj[q];
                s00 = fmaf(c4.x, v0[4 * q + 0], s00);
                s01 = fmaf(c4.y, v0[4 * q + 1], s01);
                s02 = fmaf(c4.z, v0[4 * q + 2], s02);
                s03 = fmaf(c4.w, v0[4 * q + 3], s03);
                s10 = fmaf(c4.x, v1[4 * q + 0], s10);
                s11 = fmaf(c4.y, v1[4 * q + 1], s11);
                s12 = fmaf(c4.z, v1[4 * q + 2], s12);
                s13 = fmaf(c4.w, v1[4 * q + 3], s13);
            }
            const float dot0 = (s00 + s01) + (s02 + s03);
            const float dot1 = (s10 + s11) + (s12 + s13);
            const float c2j = sc2[j];
            const float d0 = (v02 + c2j) - 2.0f * dot0;
            const float d1 = (v12 + c2j) - 2.0f * dot1;
            if (d0 < best0) { best0 = d0; bi0 = k0 + j; }
            if (d1 < best1) { best1 = d1; bi1 = k0 + j; }
        }
    }
    candD[kc * NVEC + n0] = best0;
    candD[kc * NVEC + n1] = best1;
    candI[kc * NVEC + n0] = bi0;
    candI[kc * NVEC + n1] = bi1;
}

// ---------------- combine chunks, write quantized_st / indices, scatter stats ----------------
__global__ __launch_bounds__(256) void gather_kernel(const float* __restrict__ z,
                                                     const float* __restrict__ cb,
                                                     const float* __restrict__ candD,
                                                     const int* __restrict__ candI,
                                                     float* __restrict__ out,
                                                     float* __restrict__ counts,
                                                     float* __restrict__ sums,
                                                     float* __restrict__ scal) {
    const int n = blockIdx.x * 256 + threadIdx.x;
    float best = 3.5e38f;
    int bi = 0;
#pragma unroll
    for (int kc = 0; kc < NKCH; ++kc) {
        float dv = candD[kc * NVEC + n];
        int iv = candI[kc * NVEC + n];
        if (dv < best) { best = dv; bi = iv; }
    }
    out[OFF_IDX + n] = (float)bi;
    atomicAdd(&counts[bi], 1.0f);

    const int b = n >> 10, h = n & 1023;
    const float* zp = z + (size_t)b * BPLANE + h;
    const float* cp = cb + (size_t)bi * DIMV;
    float* qp = out + OFF_Q + (size_t)b * BPLANE + h;
    float acc = 0.f;
#pragma unroll
    for (int c = 0; c < DIMV; ++c) {
        float zv = zp[c * HW];
        float q = cp[c];
        float df = q - zv;          // quantized - z
        acc = fmaf(df, df, acc);
        qp[c * HW] = zv + df;       // z + (quantized - z)  (straight-through)
        atomicAdd(&sums[bi * DIMV + c], zv);
    }
    for (int off = 32; off > 0; off >>= 1) acc += __shfl_down(acc, off, 64);
    __shared__ float red[4];
    if ((threadIdx.x & 63) == 0) red[threadIdx.x >> 6] = acc;
    __syncthreads();
    if (threadIdx.x == 0) atomicAdd(&scal[0], (red[0] + red[1]) + (red[2] + red[3]));
}

// ---------------- new_embed_avg ----------------
__global__ __launch_bounds__(256) void emavec_kernel(const float* __restrict__ ea,
                                                     const float* __restrict__ sums,
                                                     float* __restrict__ out) {
    const int i = blockIdx.x * 256 + threadIdx.x;  // < 524288
    out[OFF_NEA + i] = 0.99f * ea[i] + 0.01f * sums[i];
}

// ---------------- new_cluster_size + scalar stats partials ----------------
__global__ __launch_bounds__(256) void stats_kernel(const float* __restrict__ cs,
                                                    const float* __restrict__ counts,
                                                    float* __restrict__ out,
                                                    float* __restrict__ scal) {
    const int k = blockIdx.x * 256 + threadIdx.x;  // < 8192
    const float cnt = counts[k];
    float ncs = 0.99f * cs[k] + 0.01f * cnt;
    out[OFF_NCS + k] = ncs;
    float p = cnt * (1.0f / 32768.0f);
    float pl = p * logf(p + 1e-10f);
    float act = (cnt > 0.f) ? 1.f : 0.f;
    for (int off = 32; off > 0; off >>= 1) {
        ncs += __shfl_down(ncs, off, 64);
        pl  += __shfl_down(pl,  off, 64);
        act += __shfl_down(act, off, 64);
    }
    __shared__ float r0[4], r1[4], r2[4];
    const int w = threadIdx.x >> 6;
    if ((threadIdx.x & 63) == 0) { r0[w] = ncs; r1[w] = pl; r2[w] = act; }
    __syncthreads();
    if (threadIdx.x == 0) {
        atomicAdd(&scal[1], (r0[0] + r0[1]) + (r0[2] + r0[3]));
        atomicAdd(&scal[2], (r1[0] + r1[1]) + (r1[2] + r1[3]));
        atomicAdd(&scal[3], (r2[0] + r2[1]) + (r2[2] + r2[3]));
    }
}

// ---------------- new_codebook + scalars ----------------
__global__ __launch_bounds__(256) void final_kernel(float* __restrict__ out,
                                                    const float* __restrict__ scal) {
    const int i = blockIdx.x * 256 + threadIdx.x;  // < 524288
    const float nt = scal[1];
    const int k = i >> 6;
    const float ncs = out[OFF_NCS + k];
    const float sm = ((ncs + 1e-5f) / (nt + 0.08192f)) * nt;
    out[OFF_NCB + i] = out[OFF_NEA + i] / sm;
    if (i == 0) {
        out[OFF_LOSS] = scal[0] * (1.0f / 2097152.0f);
        out[OFF_PPL]  = expf(-scal[2]);
        out[OFF_ACT]  = scal[3];
    }
}

extern "C" void kernel_launch(void* const* d_in, const int* in_sizes, int n_in,
                              void* d_out, int out_size, void* d_ws, size_t ws_size,
                              hipStream_t stream) {
    const float* z  = (const float*)d_in[0];
    const float* cb = (const float*)d_in[1];
    const float* cs = (const float*)d_in[2];
    const float* ea = (const float*)d_in[3];
    float* out = (float*)d_out;
    float* ws  = (float*)d_ws;

    float* counts = ws + WS_COUNTS;
    float* sums   = ws + WS_SUMS;
    float* scal   = ws + WS_SCAL;
    float* c2     = ws + WS_C2;
    float* candD  = ws + WS_CANDS;
    int*   candI  = (int*)(ws + WS_CANDI);

    hipMemsetAsync(d_ws, 0, WS_ZERO_BYTES, stream);
    c2_kernel<<<KC / 4, 256, 0, stream>>>(cb, c2);
    nn_kernel<<<dim3(64, 8), 256, 0, stream>>>(z, cb, c2, candD, candI);
    gather_kernel<<<NVEC / 256, 256, 0, stream>>>(z, cb, candD, candI, out, counts, sums, scal);
    emavec_kernel<<<524288 / 256, 256, 0, stream>>>(ea, sums, out);
    stats_kernel<<<KC / 256, 256, 0, stream>>>(cs, counts, out, scal);
    final_kernel<<<524288 / 256, 256, 0, stream>>>(out, scal);
}

// Round 2
// 442.168 us; speedup vs baseline: 1.5724x; 1.5724x over previous
//
#include <hip/hip_runtime.h>
#include <math.h>

typedef unsigned short u16;
typedef unsigned int u32;
typedef __attribute__((ext_vector_type(8))) short short8;
typedef __attribute__((ext_vector_type(4))) float f32x4;

#define NVEC   32768
#define DIMV   64
#define KC     8192
#define NKCH   4
#define CHK    2048
#define HW     1024
#define BPLANE 65536

// output offsets (floats)
#define OFF_Q    0
#define OFF_IDX  2097152
#define OFF_LOSS 2129920
#define OFF_PPL  2129921
#define OFF_ACT  2129922
#define OFF_NCB  2129923
#define OFF_NCS  2654211
#define OFF_NEA  2662403

// workspace offsets (floats)
#define WS_COUNTS 0        // 8192
#define WS_SCAL   8192     // 8
#define WS_C2     8200     // 8192
#define WS_CANDD  16392    // 4*32768 = 131072
#define WS_CANDI  147464   // 131072
#define WS_SHARED 278536   // sums (524288) aliases cb splits (dead after nn)
#define WS_CBH    278536   // 262144 floats = 524288 u16
#define WS_CBM    540680
#define WS_CBL    802824   // ends 1064968 floats = 4.26 MB (same as round-1)

__device__ __forceinline__ u16 f2bf(float x) {
    u32 u = __float_as_uint(x);
    u += 0x7fffu + ((u >> 16) & 1u);   // RNE
    return (u16)(u >> 16);
}
__device__ __forceinline__ float bf2f(u16 h) {
    return __uint_as_float(((u32)h) << 16);
}

// ---------------- codebook bf16 3-split + c2 ----------------
__global__ __launch_bounds__(256) void cbsplit_kernel(const float* __restrict__ cb,
                                                      u16* __restrict__ cbh,
                                                      u16* __restrict__ cbm,
                                                      u16* __restrict__ cbl,
                                                      float* __restrict__ c2) {
    const int t = threadIdx.x;
    const int k = blockIdx.x * 4 + (t >> 6);
    const int d = t & 63;
    const int idx = k * DIMV + d;
    float x = cb[idx];
    u16 hb = f2bf(x);  float fh = bf2f(hb);
    float r1 = x - fh; u16 mb = f2bf(r1); float fm = bf2f(mb);
    float r2 = r1 - fm; u16 lb = f2bf(r2);
    cbh[idx] = hb; cbm[idx] = mb; cbl[idx] = lb;
    float s = x * x;
    for (int off = 32; off > 0; off >>= 1) s += __shfl_down(s, off, 64);
    if (d == 0) c2[k] = s;
}

// ---------------- MFMA nearest-neighbor search ----------------
// block = 4 waves; wave owns 64 vectors (4 M-tiles of 16), block-chunk = 2048 codes.
// acc(16x16x32 bf16, 6-term split) = dot - 0.5*c2  -> argmax acc == argmin distance.
__global__ __launch_bounds__(256, 2) void nn_kernel(const float* __restrict__ z,
                                                    const u16* __restrict__ cbh,
                                                    const u16* __restrict__ cbm,
                                                    const u16* __restrict__ cbl,
                                                    const float* __restrict__ c2,
                                                    float* __restrict__ candD,
                                                    int* __restrict__ candI) {
    const int l  = threadIdx.x & 63;
    const int w  = threadIdx.x >> 6;
    const int vg = blockIdx.x;      // 0..127 vector groups (256 vecs)
    const int kc = blockIdx.y;      // 0..3 code chunks (2048 codes)
    const int m0 = vg * 256 + w * 64;
    const int lr = l & 15;          // A-row / B-col / D-col lane index
    const int lg = l >> 4;          // k-half selector

    // ---- A fragments: 4 Mtiles x {h,m,l} x 2 ksteps, built from z in-register ----
    short8 A[4][3][2];
#pragma unroll
    for (int i = 0; i < 4; ++i) {
        const int vec = m0 + i * 16 + lr;
        const float* zp = z + (size_t)(vec >> 10) * BPLANE + (vec & 1023);
#pragma unroll
        for (int s = 0; s < 2; ++s) {
            short8 ah, am, al;
#pragma unroll
            for (int e = 0; e < 8; ++e) {
                const int k = s * 32 + lg * 8 + e;
                float x = zp[k * HW];
                u16 hb = f2bf(x);   float fh = bf2f(hb);
                float r1 = x - fh;  u16 mb = f2bf(r1); float fm = bf2f(mb);
                float r2 = r1 - fm; u16 lb = f2bf(r2);
                ah[e] = (short)hb; am[e] = (short)mb; al[e] = (short)lb;
            }
            A[i][0][s] = ah; A[i][1][s] = am; A[i][2][s] = al;
        }
    }

    float bestv[4][4];
    int   bestn[4][4];
#pragma unroll
    for (int i = 0; i < 4; ++i)
#pragma unroll
        for (int r = 0; r < 4; ++r) { bestv[i][r] = -3.4e38f; bestn[i][r] = 0; }

    const int code_base = kc * CHK;
    const u16* ph = cbh + (size_t)(code_base + lr) * DIMV + lg * 8;
    const u16* pm = cbm + (size_t)(code_base + lr) * DIMV + lg * 8;
    const u16* pl = cbl + (size_t)(code_base + lr) * DIMV + lg * 8;
    const float* pc2 = c2 + code_base + lr;

    for (int nt = 0; nt < CHK / 16; ++nt) {
        const int to = nt * 16 * DIMV;
        const float cm = -0.5f * pc2[nt * 16];
        short8 Bh0 = *(const short8*)(ph + to);
        short8 Bh1 = *(const short8*)(ph + to + 32);
        short8 Bm0 = *(const short8*)(pm + to);
        short8 Bm1 = *(const short8*)(pm + to + 32);
        short8 Bl0 = *(const short8*)(pl + to);
        short8 Bl1 = *(const short8*)(pl + to + 32);
#pragma unroll
        for (int i = 0; i < 4; ++i) {
            f32x4 acc = {cm, cm, cm, cm};
            acc = __builtin_amdgcn_mfma_f32_16x16x32_bf16(A[i][0][0], Bh0, acc, 0, 0, 0);
            acc = __builtin_amdgcn_mfma_f32_16x16x32_bf16(A[i][0][1], Bh1, acc, 0, 0, 0);
            acc = __builtin_amdgcn_mfma_f32_16x16x32_bf16(A[i][1][0], Bh0, acc, 0, 0, 0);
            acc = __builtin_amdgcn_mfma_f32_16x16x32_bf16(A[i][1][1], Bh1, acc, 0, 0, 0);
            acc = __builtin_amdgcn_mfma_f32_16x16x32_bf16(A[i][0][0], Bm0, acc, 0, 0, 0);
            acc = __builtin_amdgcn_mfma_f32_16x16x32_bf16(A[i][0][1], Bm1, acc, 0, 0, 0);
            acc = __builtin_amdgcn_mfma_f32_16x16x32_bf16(A[i][1][0], Bm0, acc, 0, 0, 0);
            acc = __builtin_amdgcn_mfma_f32_16x16x32_bf16(A[i][1][1], Bm1, acc, 0, 0, 0);
            acc = __builtin_amdgcn_mfma_f32_16x16x32_bf16(A[i][2][0], Bh0, acc, 0, 0, 0);
            acc = __builtin_amdgcn_mfma_f32_16x16x32_bf16(A[i][2][1], Bh1, acc, 0, 0, 0);
            acc = __builtin_amdgcn_mfma_f32_16x16x32_bf16(A[i][0][0], Bl0, acc, 0, 0, 0);
            acc = __builtin_amdgcn_mfma_f32_16x16x32_bf16(A[i][0][1], Bl1, acc, 0, 0, 0);
#pragma unroll
            for (int r = 0; r < 4; ++r) {
                float a = acc[r];
                if (a > bestv[i][r]) { bestv[i][r] = a; bestn[i][r] = nt; }
            }
        }
    }

    // reduce across the 16 lanes of each column group; first-index tie-break
#pragma unroll
    for (int i = 0; i < 4; ++i)
#pragma unroll
        for (int r = 0; r < 4; ++r) {
            float v = bestv[i][r];
            int idx = bestn[i][r] * 16 + lr;
#pragma unroll
            for (int mk = 1; mk < 16; mk <<= 1) {
                float ov = __shfl_xor(v, mk, 64);
                int   oi = __shfl_xor(idx, mk, 64);
                if (ov > v || (ov == v && oi < idx)) { v = ov; idx = oi; }
            }
            if (lr == 0) {
                const int vec = m0 + i * 16 + lg * 4 + r;
                candD[kc * NVEC + vec] = -v;            // = 0.5*c2 - dot, monotone in d
                candI[kc * NVEC + vec] = code_base + idx;
            }
        }
}

// ---------------- combine chunks, write quantized_st / indices, scatter stats ----------------
__global__ __launch_bounds__(256) void gather_kernel(const float* __restrict__ z,
                                                     const float* __restrict__ cb,
                                                     const float* __restrict__ candD,
                                                     const int* __restrict__ candI,
                                                     float* __restrict__ out,
                                                     float* __restrict__ counts,
                                                     float* __restrict__ sums,
                                                     float* __restrict__ scal) {
    const int n = blockIdx.x * 256 + threadIdx.x;
    float best = 3.5e38f;
    int bi = 0;
#pragma unroll
    for (int kc = 0; kc < NKCH; ++kc) {
        float dv = candD[kc * NVEC + n];
        int iv = candI[kc * NVEC + n];
        if (dv < best) { best = dv; bi = iv; }
    }
    out[OFF_IDX + n] = (float)bi;
    atomicAdd(&counts[bi], 1.0f);

    const int b = n >> 10, h = n & 1023;
    const float* zp = z + (size_t)b * BPLANE + h;
    const float* cp = cb + (size_t)bi * DIMV;
    float* qp = out + OFF_Q + (size_t)b * BPLANE + h;
    float acc = 0.f;
#pragma unroll
    for (int c = 0; c < DIMV; ++c) {
        float zv = zp[c * HW];
        float q = cp[c];
        float df = q - zv;
        acc = fmaf(df, df, acc);
        qp[c * HW] = zv + df;
        atomicAdd(&sums[bi * DIMV + c], zv);
    }
    for (int off = 32; off > 0; off >>= 1) acc += __shfl_down(acc, off, 64);
    __shared__ float red[4];
    if ((threadIdx.x & 63) == 0) red[threadIdx.x >> 6] = acc;
    __syncthreads();
    if (threadIdx.x == 0) atomicAdd(&scal[0], (red[0] + red[1]) + (red[2] + red[3]));
}

// ---------------- new_embed_avg ----------------
__global__ __launch_bounds__(256) void emavec_kernel(const float* __restrict__ ea,
                                                     const float* __restrict__ sums,
                                                     float* __restrict__ out) {
    const int i = blockIdx.x * 256 + threadIdx.x;
    out[OFF_NEA + i] = 0.99f * ea[i] + 0.01f * sums[i];
}

// ---------------- new_cluster_size + scalar stats partials ----------------
__global__ __launch_bounds__(256) void stats_kernel(const float* __restrict__ cs,
                                                    const float* __restrict__ counts,
                                                    float* __restrict__ out,
                                                    float* __restrict__ scal) {
    const int k = blockIdx.x * 256 + threadIdx.x;
    const float cnt = counts[k];
    float ncs = 0.99f * cs[k] + 0.01f * cnt;
    out[OFF_NCS + k] = ncs;
    float p = cnt * (1.0f / 32768.0f);
    float pl = p * logf(p + 1e-10f);
    float act = (cnt > 0.f) ? 1.f : 0.f;
    for (int off = 32; off > 0; off >>= 1) {
        ncs += __shfl_down(ncs, off, 64);
        pl  += __shfl_down(pl,  off, 64);
        act += __shfl_down(act, off, 64);
    }
    __shared__ float r0[4], r1[4], r2[4];
    const int w = threadIdx.x >> 6;
    if ((threadIdx.x & 63) == 0) { r0[w] = ncs; r1[w] = pl; r2[w] = act; }
    __syncthreads();
    if (threadIdx.x == 0) {
        atomicAdd(&scal[1], (r0[0] + r0[1]) + (r0[2] + r0[3]));
        atomicAdd(&scal[2], (r1[0] + r1[1]) + (r1[2] + r1[3]));
        atomicAdd(&scal[3], (r2[0] + r2[1]) + (r2[2] + r2[3]));
    }
}

// ---------------- new_codebook + scalars ----------------
__global__ __launch_bounds__(256) void final_kernel(float* __restrict__ out,
                                                    const float* __restrict__ scal) {
    const int i = blockIdx.x * 256 + threadIdx.x;
    const float nt = scal[1];
    const int k = i >> 6;
    const float ncs = out[OFF_NCS + k];
    const float sm = ((ncs + 1e-5f) / (nt + 0.08192f)) * nt;
    out[OFF_NCB + i] = out[OFF_NEA + i] / sm;
    if (i == 0) {
        out[OFF_LOSS] = scal[0] * (1.0f / 2097152.0f);
        out[OFF_PPL]  = expf(-scal[2]);
        out[OFF_ACT]  = scal[3];
    }
}

extern "C" void kernel_launch(void* const* d_in, const int* in_sizes, int n_in,
                              void* d_out, int out_size, void* d_ws, size_t ws_size,
                              hipStream_t stream) {
    const float* z  = (const float*)d_in[0];
    const float* cb = (const float*)d_in[1];
    const float* cs = (const float*)d_in[2];
    const float* ea = (const float*)d_in[3];
    float* out = (float*)d_out;
    float* ws  = (float*)d_ws;

    float* counts = ws + WS_COUNTS;
    float* scal   = ws + WS_SCAL;
    float* c2     = ws + WS_C2;
    float* candD  = ws + WS_CANDD;
    int*   candI  = (int*)(ws + WS_CANDI);
    u16*   cbh    = (u16*)(ws + WS_CBH);
    u16*   cbm    = (u16*)(ws + WS_CBM);
    u16*   cbl    = (u16*)(ws + WS_CBL);
    float* sums   = ws + WS_SHARED;   // aliases cb splits (dead after nn_kernel)

    hipMemsetAsync(ws, 0, (8192 + 8) * 4, stream);            // counts + scal
    cbsplit_kernel<<<KC / 4, 256, 0, stream>>>(cb, cbh, cbm, cbl, c2);
    nn_kernel<<<dim3(128, 4), 256, 0, stream>>>(z, cbh, cbm, cbl, c2, candD, candI);
    hipMemsetAsync(sums, 0, 524288 * 4, stream);              // sums (after nn: alias dead)
    gather_kernel<<<NVEC / 256, 256, 0, stream>>>(z, cb, candD, candI, out, counts, sums, scal);
    emavec_kernel<<<524288 / 256, 256, 0, stream>>>(ea, sums, out);
    stats_kernel<<<KC / 256, 256, 0, stream>>>(cs, counts, out, scal);
    final_kernel<<<524288 / 256, 256, 0, stream>>>(out, scal);
}

// Round 3
// 296.900 us; speedup vs baseline: 2.3418x; 1.4893x over previous
//
#include <hip/hip_runtime.h>
#include <math.h>

typedef unsigned short u16;
typedef unsigned int u32;
typedef __attribute__((ext_vector_type(8))) short short8;
typedef __attribute__((ext_vector_type(4))) float f32x4;

#define NVEC   32768
#define DIMV   64
#define KC     8192
#define NKCH   4
#define CHK    2048
#define HW     1024
#define BPLANE 65536

// output offsets (floats)
#define OFF_Q    0
#define OFF_IDX  2097152
#define OFF_LOSS 2129920
#define OFF_PPL  2129921
#define OFF_ACT  2129922
#define OFF_NCB  2129923
#define OFF_NCS  2654211
#define OFF_NEA  2662403

// workspace offsets (floats)
#define WS_COUNTS 0        // 8192
#define WS_SCAL   8192     // 8
#define WS_C2     8200     // 8192
#define WS_CANDD  16392    // 131072 (perm aliases this after gather)
#define WS_CANDI  147464   // 131072 (offs aliases this after gather)
#define WS_CBH    278536   // cb splits; sums aliases this after nn
#define WS_CBM    540680
#define WS_CBL    802824   // ends 1064968 floats = 4.26 MB

__device__ __forceinline__ u16 f2bf(float x) {
    u32 u = __float_as_uint(x);
    u += 0x7fffu + ((u >> 16) & 1u);   // RNE
    return (u16)(u >> 16);
}
__device__ __forceinline__ float bf2f(u16 h) {
    return __uint_as_float(((u32)h) << 16);
}

// ---------------- codebook bf16 3-split + c2 ----------------
__global__ __launch_bounds__(256) void cbsplit_kernel(const float* __restrict__ cb,
                                                      u16* __restrict__ cbh,
                                                      u16* __restrict__ cbm,
                                                      u16* __restrict__ cbl,
                                                      float* __restrict__ c2) {
    const int t = threadIdx.x;
    const int k = blockIdx.x * 4 + (t >> 6);
    const int d = t & 63;
    const int idx = k * DIMV + d;
    float x = cb[idx];
    u16 hb = f2bf(x);  float fh = bf2f(hb);
    float r1 = x - fh; u16 mb = f2bf(r1); float fm = bf2f(mb);
    float r2 = r1 - fm; u16 lb = f2bf(r2);
    cbh[idx] = hb; cbm[idx] = mb; cbl[idx] = lb;
    float s = x * x;
    for (int off = 32; off > 0; off >>= 1) s += __shfl_down(s, off, 64);
    if (d == 0) c2[k] = s;
}

// ---------------- MFMA nearest-neighbor search ----------------
__global__ __launch_bounds__(256, 2) void nn_kernel(const float* __restrict__ z,
                                                    const u16* __restrict__ cbh,
                                                    const u16* __restrict__ cbm,
                                                    const u16* __restrict__ cbl,
                                                    const float* __restrict__ c2,
                                                    float* __restrict__ candD,
                                                    int* __restrict__ candI) {
    const int l  = threadIdx.x & 63;
    const int w  = threadIdx.x >> 6;
    const int vg = blockIdx.x;      // 0..127 vector groups (256 vecs)
    const int kc = blockIdx.y;      // 0..3 code chunks (2048 codes)
    const int m0 = vg * 256 + w * 64;
    const int lr = l & 15;
    const int lg = l >> 4;

    short8 A[4][3][2];
#pragma unroll
    for (int i = 0; i < 4; ++i) {
        const int vec = m0 + i * 16 + lr;
        const float* zp = z + (size_t)(vec >> 10) * BPLANE + (vec & 1023);
#pragma unroll
        for (int s = 0; s < 2; ++s) {
            short8 ah, am, al;
#pragma unroll
            for (int e = 0; e < 8; ++e) {
                const int k = s * 32 + lg * 8 + e;
                float x = zp[k * HW];
                u16 hb = f2bf(x);   float fh = bf2f(hb);
                float r1 = x - fh;  u16 mb = f2bf(r1); float fm = bf2f(mb);
                float r2 = r1 - fm; u16 lb = f2bf(r2);
                ah[e] = (short)hb; am[e] = (short)mb; al[e] = (short)lb;
            }
            A[i][0][s] = ah; A[i][1][s] = am; A[i][2][s] = al;
        }
    }

    float bestv[4][4];
    int   bestn[4][4];
#pragma unroll
    for (int i = 0; i < 4; ++i)
#pragma unroll
        for (int r = 0; r < 4; ++r) { bestv[i][r] = -3.4e38f; bestn[i][r] = 0; }

    const int code_base = kc * CHK;
    const u16* ph = cbh + (size_t)(code_base + lr) * DIMV + lg * 8;
    const u16* pm = cbm + (size_t)(code_base + lr) * DIMV + lg * 8;
    const u16* pl = cbl + (size_t)(code_base + lr) * DIMV + lg * 8;
    const float* pc2 = c2 + code_base + lr;

    for (int nt = 0; nt < CHK / 16; ++nt) {
        const int to = nt * 16 * DIMV;
        const float cm = -0.5f * pc2[nt * 16];
        short8 Bh0 = *(const short8*)(ph + to);
        short8 Bh1 = *(const short8*)(ph + to + 32);
        short8 Bm0 = *(const short8*)(pm + to);
        short8 Bm1 = *(const short8*)(pm + to + 32);
        short8 Bl0 = *(const short8*)(pl + to);
        short8 Bl1 = *(const short8*)(pl + to + 32);
#pragma unroll
        for (int i = 0; i < 4; ++i) {
            f32x4 acc = {cm, cm, cm, cm};
            acc = __builtin_amdgcn_mfma_f32_16x16x32_bf16(A[i][0][0], Bh0, acc, 0, 0, 0);
            acc = __builtin_amdgcn_mfma_f32_16x16x32_bf16(A[i][0][1], Bh1, acc, 0, 0, 0);
            acc = __builtin_amdgcn_mfma_f32_16x16x32_bf16(A[i][1][0], Bh0, acc, 0, 0, 0);
            acc = __builtin_amdgcn_mfma_f32_16x16x32_bf16(A[i][1][1], Bh1, acc, 0, 0, 0);
            acc = __builtin_amdgcn_mfma_f32_16x16x32_bf16(A[i][0][0], Bm0, acc, 0, 0, 0);
            acc = __builtin_amdgcn_mfma_f32_16x16x32_bf16(A[i][0][1], Bm1, acc, 0, 0, 0);
            acc = __builtin_amdgcn_mfma_f32_16x16x32_bf16(A[i][1][0], Bm0, acc, 0, 0, 0);
            acc = __builtin_amdgcn_mfma_f32_16x16x32_bf16(A[i][1][1], Bm1, acc, 0, 0, 0);
            acc = __builtin_amdgcn_mfma_f32_16x16x32_bf16(A[i][2][0], Bh0, acc, 0, 0, 0);
            acc = __builtin_amdgcn_mfma_f32_16x16x32_bf16(A[i][2][1], Bh1, acc, 0, 0, 0);
            acc = __builtin_amdgcn_mfma_f32_16x16x32_bf16(A[i][0][0], Bl0, acc, 0, 0, 0);
            acc = __builtin_amdgcn_mfma_f32_16x16x32_bf16(A[i][0][1], Bl1, acc, 0, 0, 0);
#pragma unroll
            for (int r = 0; r < 4; ++r) {
                float a = acc[r];
                if (a > bestv[i][r]) { bestv[i][r] = a; bestn[i][r] = nt; }
            }
        }
    }

#pragma unroll
    for (int i = 0; i < 4; ++i)
#pragma unroll
        for (int r = 0; r < 4; ++r) {
            float v = bestv[i][r];
            int idx = bestn[i][r] * 16 + lr;
#pragma unroll
            for (int mk = 1; mk < 16; mk <<= 1) {
                float ov = __shfl_xor(v, mk, 64);
                int   oi = __shfl_xor(idx, mk, 64);
                if (ov > v || (ov == v && oi < idx)) { v = ov; idx = oi; }
            }
            if (lr == 0) {
                const int vec = m0 + i * 16 + lg * 4 + r;
                candD[kc * NVEC + vec] = -v;
                candI[kc * NVEC + vec] = code_base + idx;
            }
        }
}

// ---------------- combine chunks, write quantized_st / indices, count atomics ----------------
__global__ __launch_bounds__(256) void gather_kernel(const float* __restrict__ z,
                                                     const float* __restrict__ cb,
                                                     const float* __restrict__ candD,
                                                     const int* __restrict__ candI,
                                                     float* __restrict__ out,
                                                     float* __restrict__ counts,
                                                     float* __restrict__ scal) {
    const int n = blockIdx.x * 256 + threadIdx.x;
    float best = 3.5e38f;
    int bi = 0;
#pragma unroll
    for (int kc = 0; kc < NKCH; ++kc) {
        float dv = candD[kc * NVEC + n];
        int iv = candI[kc * NVEC + n];
        if (dv < best) { best = dv; bi = iv; }
    }
    out[OFF_IDX + n] = (float)bi;
    atomicAdd(&counts[bi], 1.0f);

    const int b = n >> 10, h = n & 1023;
    const float* zp = z + (size_t)b * BPLANE + h;
    const float* cp = cb + (size_t)bi * DIMV;
    float* qp = out + OFF_Q + (size_t)b * BPLANE + h;
    float acc = 0.f;
#pragma unroll
    for (int c = 0; c < DIMV; ++c) {
        float zv = zp[c * HW];
        float q = cp[c];
        float df = q - zv;
        acc = fmaf(df, df, acc);
        qp[c * HW] = zv + df;
    }
    for (int off = 32; off > 0; off >>= 1) acc += __shfl_down(acc, off, 64);
    __shared__ float red[4];
    if ((threadIdx.x & 63) == 0) red[threadIdx.x >> 6] = acc;
    __syncthreads();
    if (threadIdx.x == 0) atomicAdd(&scal[0], (red[0] + red[1]) + (red[2] + red[3]));
}

// ---------------- exclusive prefix scan of counts -> offs (bucket starts) ----------------
__global__ __launch_bounds__(256) void prefix_kernel(const float* __restrict__ counts,
                                                     int* __restrict__ offs) {
    __shared__ int part[256];
    const int t = threadIdx.x;
    const int base = t * 32;
    int loc[32];
    int s = 0;
#pragma unroll
    for (int j = 0; j < 32; ++j) { loc[j] = s; s += (int)counts[base + j]; }
    part[t] = s;
    __syncthreads();
    for (int off = 1; off < 256; off <<= 1) {
        int v = (t >= off) ? part[t - off] : 0;
        __syncthreads();
        part[t] += v;
        __syncthreads();
    }
    const int excl = part[t] - s;
#pragma unroll
    for (int j = 0; j < 32; ++j) offs[base + j] = excl + loc[j];
}

// ---------------- scatter vector ids into buckets ----------------
__global__ __launch_bounds__(256) void scatter_kernel(const float* __restrict__ outIdx,
                                                      int* __restrict__ offs,
                                                      int* __restrict__ perm) {
    const int n = blockIdx.x * 256 + threadIdx.x;
    const int bi = (int)outIdx[n];
    const int pos = atomicAdd(&offs[bi], 1);
    perm[pos] = n;
}

// ---------------- per-code segmented sum (wave = code, lane = channel) ----------------
__global__ __launch_bounds__(256) void segsum_kernel(const float* __restrict__ z,
                                                     const float* __restrict__ counts,
                                                     const int* __restrict__ offs,
                                                     const int* __restrict__ perm,
                                                     float* __restrict__ sums) {
    const int w = threadIdx.x >> 6;
    const int c = threadIdx.x & 63;
    const int k = blockIdx.x * 4 + w;
    const int end = offs[k];               // post-scatter: bucket end
    const int cnt = (int)counts[k];
    float s = 0.f;
    for (int m = end - cnt; m < end; ++m) {
        const int n = perm[m];
        s += z[(size_t)(n >> 10) * BPLANE + (size_t)c * HW + (n & 1023)];
    }
    sums[k * DIMV + c] = s;
}

// ---------------- new_embed_avg ----------------
__global__ __launch_bounds__(256) void emavec_kernel(const float* __restrict__ ea,
                                                     const float* __restrict__ sums,
                                                     float* __restrict__ out) {
    const int i = blockIdx.x * 256 + threadIdx.x;
    out[OFF_NEA + i] = 0.99f * ea[i] + 0.01f * sums[i];
}

// ---------------- new_cluster_size + scalar stats partials ----------------
__global__ __launch_bounds__(256) void stats_kernel(const float* __restrict__ cs,
                                                    const float* __restrict__ counts,
                                                    float* __restrict__ out,
                                                    float* __restrict__ scal) {
    const int k = blockIdx.x * 256 + threadIdx.x;
    const float cnt = counts[k];
    float ncs = 0.99f * cs[k] + 0.01f * cnt;
    out[OFF_NCS + k] = ncs;
    float p = cnt * (1.0f / 32768.0f);
    float pl = p * logf(p + 1e-10f);
    float act = (cnt > 0.f) ? 1.f : 0.f;
    for (int off = 32; off > 0; off >>= 1) {
        ncs += __shfl_down(ncs, off, 64);
        pl  += __shfl_down(pl,  off, 64);
        act += __shfl_down(act, off, 64);
    }
    __shared__ float r0[4], r1[4], r2[4];
    const int w = threadIdx.x >> 6;
    if ((threadIdx.x & 63) == 0) { r0[w] = ncs; r1[w] = pl; r2[w] = act; }
    __syncthreads();
    if (threadIdx.x == 0) {
        atomicAdd(&scal[1], (r0[0] + r0[1]) + (r0[2] + r0[3]));
        atomicAdd(&scal[2], (r1[0] + r1[1]) + (r1[2] + r1[3]));
        atomicAdd(&scal[3], (r2[0] + r2[1]) + (r2[2] + r2[3]));
    }
}

// ---------------- new_codebook + scalars ----------------
__global__ __launch_bounds__(256) void final_kernel(float* __restrict__ out,
                                                    const float* __restrict__ scal) {
    const int i = blockIdx.x * 256 + threadIdx.x;
    const float nt = scal[1];
    const int k = i >> 6;
    const float ncs = out[OFF_NCS + k];
    const float sm = ((ncs + 1e-5f) / (nt + 0.08192f)) * nt;
    out[OFF_NCB + i] = out[OFF_NEA + i] / sm;
    if (i == 0) {
        out[OFF_LOSS] = scal[0] * (1.0f / 2097152.0f);
        out[OFF_PPL]  = expf(-scal[2]);
        out[OFF_ACT]  = scal[3];
    }
}

extern "C" void kernel_launch(void* const* d_in, const int* in_sizes, int n_in,
                              void* d_out, int out_size, void* d_ws, size_t ws_size,
                              hipStream_t stream) {
    const float* z  = (const float*)d_in[0];
    const float* cb = (const float*)d_in[1];
    const float* cs = (const float*)d_in[2];
    const float* ea = (const float*)d_in[3];
    float* out = (float*)d_out;
    float* ws  = (float*)d_ws;

    float* counts = ws + WS_COUNTS;
    float* scal   = ws + WS_SCAL;
    float* c2     = ws + WS_C2;
    float* candD  = ws + WS_CANDD;
    int*   candI  = (int*)(ws + WS_CANDI);
    u16*   cbh    = (u16*)(ws + WS_CBH);
    u16*   cbm    = (u16*)(ws + WS_CBM);
    u16*   cbl    = (u16*)(ws + WS_CBL);
    int*   perm   = (int*)(ws + WS_CANDD);   // aliases candD (dead after gather)
    int*   offs   = (int*)(ws + WS_CANDI);   // aliases candI (dead after gather)
    float* sums   = ws + WS_CBH;             // aliases cb splits (dead after nn)

    hipMemsetAsync(ws, 0, (8192 + 8) * 4, stream);            // counts + scal
    cbsplit_kernel<<<KC / 4, 256, 0, stream>>>(cb, cbh, cbm, cbl, c2);
    nn_kernel<<<dim3(128, 4), 256, 0, stream>>>(z, cbh, cbm, cbl, c2, candD, candI);
    gather_kernel<<<NVEC / 256, 256, 0, stream>>>(z, cb, candD, candI, out, counts, scal);
    prefix_kernel<<<1, 256, 0, stream>>>(counts, offs);
    scatter_kernel<<<NVEC / 256, 256, 0, stream>>>(out + OFF_IDX, offs, perm);
    segsum_kernel<<<KC / 4, 256, 0, stream>>>(z, counts, offs, perm, sums);
    emavec_kernel<<<524288 / 256, 256, 0, stream>>>(ea, sums, out);
    stats_kernel<<<KC / 256, 256, 0, stream>>>(cs, counts, out, scal);
    final_kernel<<<524288 / 256, 256, 0, stream>>>(out, scal);
}